// Round 3
// baseline (898.788 us; speedup 1.0000x reference)
//
#include <hip/hip_runtime.h>
#include <stdint.h>
#include <stddef.h>

// Problem constants
#define N_ROWS 32768
#define D_IN   3000
#define KPAD   3072   // D_IN padded to multiple of 32 (zero pad)
#define H0     1024
#define H1     256
#define NCLUST 20

typedef __attribute__((ext_vector_type(8))) short short8;   // 8 x bf16 (4 VGPRs)
typedef __attribute__((ext_vector_type(4))) float f32x4;

// fp32 -> bf16 (round-to-nearest-even)
__device__ inline unsigned short f2bf(float f) {
    union { float f; unsigned u; } v; v.f = f;
    unsigned r = v.u + 0x7fffu + ((v.u >> 16) & 1u);
    return (unsigned short)(r >> 16);
}

// async global->LDS, 16B per lane; lds dest is wave-uniform base (+lane*16 implicit)
__device__ inline void async16(const unsigned short* g, unsigned short* l) {
    __builtin_amdgcn_global_load_lds(
        (const __attribute__((address_space(1))) unsigned int*)(g),
        (__attribute__((address_space(3))) unsigned int*)(l),
        16, 0, 0);
}

// ---------------------------------------------------------------------------
// x [32768 x 3000] fp32 -> xb [32768 x 3072] bf16, zero-padded cols 3000..3071
// ---------------------------------------------------------------------------
__global__ __launch_bounds__(256)
void cvt_x(const float* __restrict__ x, unsigned short* __restrict__ xb) {
    int idx = blockIdx.x * 256 + threadIdx.x;     // [0, 32768*384)
    int m  = idx / 384;
    int k8 = idx - m * 384;
    uint4 out;
    if (k8 < 375) {
        const float4 v0 = ((const float4*)x)[(size_t)m * 750 + k8 * 2];
        const float4 v1 = ((const float4*)x)[(size_t)m * 750 + k8 * 2 + 1];
        out.x = ((unsigned)f2bf(v0.x)) | (((unsigned)f2bf(v0.y)) << 16);
        out.y = ((unsigned)f2bf(v0.z)) | (((unsigned)f2bf(v0.w)) << 16);
        out.z = ((unsigned)f2bf(v1.x)) | (((unsigned)f2bf(v1.y)) << 16);
        out.w = ((unsigned)f2bf(v1.z)) | (((unsigned)f2bf(v1.w)) << 16);
    } else {
        out.x = 0u; out.y = 0u; out.z = 0u; out.w = 0u;
    }
    ((uint4*)xb)[(size_t)m * 384 + k8] = out;
}

// ---------------------------------------------------------------------------
// W [rows x cols] fp32 row-major -> outT [cols x rowsPad] bf16 (transposed)
// ---------------------------------------------------------------------------
__global__ __launch_bounds__(256)
void transpose_cvt(const float* __restrict__ W, int rows, int cols, int rowsPad,
                   unsigned short* __restrict__ outT) {
    __shared__ unsigned short tile[32][33];
    const int c0 = blockIdx.x * 32;
    const int r0 = blockIdx.y * 32;
    const int tx = threadIdx.x, ty = threadIdx.y;
    #pragma unroll
    for (int i = 0; i < 4; ++i) {
        int r = r0 + ty + i * 8;
        float v = (r < rows) ? W[(size_t)r * cols + c0 + tx] : 0.0f;
        tile[ty + i * 8][tx] = f2bf(v);
    }
    __syncthreads();
    #pragma unroll
    for (int i = 0; i < 4; ++i) {
        int c = c0 + ty + i * 8;
        outT[(size_t)c * rowsPad + r0 + tx] = tile[tx][ty + i * 8];
    }
}

// ---------------------------------------------------------------------------
// GEMM1: h = silu(xb[32768 x 3072] @ w1t[1024 x 3072]^T + b1) -> bf16
// 128x256 block tile, BK=32, 4 waves (2x2), wave tile 64x128, dbuf LDS,
// one barrier/iter. XCD-aware swizzle: the 4 n-blocks sharing an A panel are
// dispatch-consecutive on the same XCD (assumes round-robin XCD = L%8; if the
// mapping differs, they are still dispatch-adjacent -> L3 temporal locality).
// ---------------------------------------------------------------------------
__global__ __launch_bounds__(256, 2)
void gemm1(const unsigned short* __restrict__ A,
           const unsigned short* __restrict__ Bt,
           const float* __restrict__ bias,
           unsigned short* __restrict__ Hout)
{
    constexpr int K  = KPAD;   // 3072
    constexpr int Nn = H0;     // 1024

    __shared__ unsigned short sA[2][128 * 32];
    __shared__ unsigned short sB[2][256 * 32];

    // swizzle: 1024 blocks = 256 m-panels x 4 n-blocks, 8 XCDs x 32 panels
    const int L  = blockIdx.x;
    const int X  = L & 7;          // XCD under round-robin dispatch
    const int S  = L >> 3;         // sequence within XCD, 0..127
    const int m0 = (X * 32 + (S >> 2)) * 128;
    const int n0 = (S & 3) * 256;

    const int tid  = threadIdx.x;
    const int wave = tid >> 6;
    const int lane = tid & 63;
    const int wm   = wave & 1;
    const int wn   = wave >> 1;

    f32x4 acc[4][8];
    #pragma unroll
    for (int i = 0; i < 4; ++i)
        #pragma unroll
        for (int j = 0; j < 8; ++j)
            acc[i][j] = (f32x4){0.f, 0.f, 0.f, 0.f};

    const int laneRow = lane >> 2;
    const int laneCol = (lane & 3) * 8;
    const unsigned short* gA0 = A  + (size_t)(m0 + wave * 32 + laneRow) * K + laneCol;
    const unsigned short* gA1 = gA0 + (size_t)16 * K;
    const unsigned short* gB0 = Bt + (size_t)(n0 + wave * 64 + laneRow) * K + laneCol;
    const unsigned short* gB1 = gB0 + (size_t)16 * K;
    const unsigned short* gB2 = gB0 + (size_t)32 * K;
    const unsigned short* gB3 = gB0 + (size_t)48 * K;
    const int lAo = wave * 1024;
    const int lBo = wave * 2048;

    const int fa = (wm * 64  + (lane & 15)) * 32 + (lane >> 4) * 8;
    const int fb = (wn * 128 + (lane & 15)) * 32 + (lane >> 4) * 8;

    constexpr int KT = K >> 5;   // 96

    async16(gA0, &sA[0][lAo]);
    async16(gA1, &sA[0][lAo + 512]);
    async16(gB0, &sB[0][lBo]);
    async16(gB1, &sB[0][lBo + 512]);
    async16(gB2, &sB[0][lBo + 1024]);
    async16(gB3, &sB[0][lBo + 1536]);

    for (int kt = 0; kt < KT; ++kt) {
        const int buf = kt & 1;
        __syncthreads();
        if (kt + 1 < KT) {
            const int k0 = (kt + 1) << 5;
            const int nb = buf ^ 1;
            async16(gA0 + k0, &sA[nb][lAo]);
            async16(gA1 + k0, &sA[nb][lAo + 512]);
            async16(gB0 + k0, &sB[nb][lBo]);
            async16(gB1 + k0, &sB[nb][lBo + 512]);
            async16(gB2 + k0, &sB[nb][lBo + 1024]);
            async16(gB3 + k0, &sB[nb][lBo + 1536]);
        }
        short8 af[4], bf[8];
        #pragma unroll
        for (int t = 0; t < 4; ++t) af[t] = *(const short8*)&sA[buf][fa + t * 512];
        #pragma unroll
        for (int t = 0; t < 8; ++t) bf[t] = *(const short8*)&sB[buf][fb + t * 512];
        #pragma unroll
        for (int i = 0; i < 4; ++i)
            #pragma unroll
            for (int j = 0; j < 8; ++j)
                acc[i][j] = __builtin_amdgcn_mfma_f32_16x16x32_bf16(
                    af[i], bf[j], acc[i][j], 0, 0, 0);
    }

    // Epilogue. C/D: col = lane&15, row = (lane>>4)*4 + reg
    const int cr = (lane >> 4) * 4;
    const int cc = lane & 15;
    #pragma unroll
    for (int j = 0; j < 8; ++j) {
        const int col = n0 + wn * 128 + j * 16 + cc;
        const float bv = bias[col];
        #pragma unroll
        for (int i = 0; i < 4; ++i) {
            const int rowBase = m0 + wm * 64 + i * 16 + cr;
            #pragma unroll
            for (int r = 0; r < 4; ++r) {
                float v = acc[i][j][r] + bv;
                float s = v / (1.0f + __expf(-v));   // silu
                Hout[(size_t)(rowBase + r) * Nn + col] = f2bf(s);
            }
        }
    }
}

// ---------------------------------------------------------------------------
// GEMM2: z = h[32768 x 1024] @ w2t[256 x 1024]^T + b2 -> fp32
// 128x128 tile, 512 blocks (2/CU), dbuf, one barrier/iter.
// ---------------------------------------------------------------------------
__global__ __launch_bounds__(256, 2)
void gemm2(const unsigned short* __restrict__ A,
           const unsigned short* __restrict__ Bt,
           const float* __restrict__ bias,
           float* __restrict__ Zout)
{
    constexpr int K  = H0;    // 1024
    constexpr int Nn = H1;    // 256

    __shared__ unsigned short sA[2][128 * 32];
    __shared__ unsigned short sB[2][128 * 32];

    const int L  = blockIdx.x;          // 512 blocks: n-pairs consecutive
    const int m0 = (L >> 1) * 128;
    const int n0 = (L & 1) * 128;

    const int tid  = threadIdx.x;
    const int wave = tid >> 6;
    const int lane = tid & 63;
    const int wm   = wave & 1;
    const int wn   = wave >> 1;

    f32x4 acc[4][4];
    #pragma unroll
    for (int i = 0; i < 4; ++i)
        #pragma unroll
        for (int j = 0; j < 4; ++j)
            acc[i][j] = (f32x4){0.f, 0.f, 0.f, 0.f};

    const int laneRow = lane >> 2;
    const int laneCol = (lane & 3) * 8;
    const unsigned short* gA0 = A  + (size_t)(m0 + wave * 32 + laneRow) * K + laneCol;
    const unsigned short* gA1 = gA0 + (size_t)16 * K;
    const unsigned short* gB0 = Bt + (size_t)(n0 + wave * 32 + laneRow) * K + laneCol;
    const unsigned short* gB1 = gB0 + (size_t)16 * K;
    const int lo = wave * 1024;

    const int fa = (wm * 64 + (lane & 15)) * 32 + (lane >> 4) * 8;
    const int fb = (wn * 64 + (lane & 15)) * 32 + (lane >> 4) * 8;

    constexpr int KT = K >> 5;   // 32

    async16(gA0, &sA[0][lo]);
    async16(gA1, &sA[0][lo + 512]);
    async16(gB0, &sB[0][lo]);
    async16(gB1, &sB[0][lo + 512]);

    for (int kt = 0; kt < KT; ++kt) {
        const int buf = kt & 1;
        __syncthreads();
        if (kt + 1 < KT) {
            const int k0 = (kt + 1) << 5;
            const int nb = buf ^ 1;
            async16(gA0 + k0, &sA[nb][lo]);
            async16(gA1 + k0, &sA[nb][lo + 512]);
            async16(gB0 + k0, &sB[nb][lo]);
            async16(gB1 + k0, &sB[nb][lo + 512]);
        }
        short8 af[4], bf[4];
        #pragma unroll
        for (int t = 0; t < 4; ++t) af[t] = *(const short8*)&sA[buf][fa + t * 512];
        #pragma unroll
        for (int t = 0; t < 4; ++t) bf[t] = *(const short8*)&sB[buf][fb + t * 512];
        #pragma unroll
        for (int i = 0; i < 4; ++i)
            #pragma unroll
            for (int j = 0; j < 4; ++j)
                acc[i][j] = __builtin_amdgcn_mfma_f32_16x16x32_bf16(
                    af[i], bf[j], acc[i][j], 0, 0, 0);
    }

    const int cr = (lane >> 4) * 4;
    const int cc = lane & 15;
    #pragma unroll
    for (int j = 0; j < 4; ++j) {
        const int col = n0 + wn * 64 + j * 16 + cc;
        const float bv = bias[col];
        #pragma unroll
        for (int i = 0; i < 4; ++i) {
            const int rowBase = m0 + wm * 64 + i * 16 + cr;
            #pragma unroll
            for (int r = 0; r < 4; ++r)
                Zout[(size_t)(rowBase + r) * Nn + col] = acc[i][j][r] + bv;
        }
    }
}

// ---------------------------------------------------------------------------
// Soft-assign: q[n,k] = (1 + ||z_n - c_k||^2)^-1, row-normalized (V=1).
// ---------------------------------------------------------------------------
__global__ __launch_bounds__(256)
void cluster_kernel(const float* __restrict__ z, const float* __restrict__ clusters,
                    float* __restrict__ q) {
    __shared__ float sc[NCLUST * H1];   // 20 KB
    const int tid = threadIdx.x;
    for (int i = tid; i < NCLUST * H1; i += 256) sc[i] = clusters[i];
    __syncthreads();

    const int wave = tid >> 6, lane = tid & 63;
    const int row = blockIdx.x * 4 + wave;

    const float4 zv = ((const float4*)(z + (size_t)row * H1))[lane];

    float myq = 0.0f, qsum = 0.0f;
    #pragma unroll
    for (int k = 0; k < NCLUST; ++k) {
        const float4 cv = ((const float4*)(sc + k * H1))[lane];
        float dx = zv.x - cv.x, dy = zv.y - cv.y;
        float dz = zv.z - cv.z, dw = zv.w - cv.w;
        float p = dx * dx + dy * dy + dz * dz + dw * dw;
        #pragma unroll
        for (int s = 32; s >= 1; s >>= 1) p += __shfl_xor(p, s, 64);
        float qk = 1.0f / (1.0f + p);   // V=1
        qsum += qk;
        myq = (lane == k) ? qk : myq;
    }
    if (lane < NCLUST) q[(size_t)row * NCLUST + lane] = myq / qsum;
}

// ---------------------------------------------------------------------------
extern "C" void kernel_launch(void* const* d_in, const int* in_sizes, int n_in,
                              void* d_out, int out_size, void* d_ws, size_t ws_size,
                              hipStream_t stream) {
    const float* x        = (const float*)d_in[0];
    const float* W1       = (const float*)d_in[1];
    const float* b1       = (const float*)d_in[2];
    const float* W2       = (const float*)d_in[3];
    const float* b2       = (const float*)d_in[4];
    const float* clusters = (const float*)d_in[5];
    float* out = (float*)d_out;   // [32768*256 z fp32][32768*20 q fp32]

    unsigned short* xb  = (unsigned short*)d_ws;                  // 32768*3072 bf16
    unsigned short* w1t = xb  + (size_t)N_ROWS * KPAD;            // 1024*3072 bf16
    unsigned short* w2t = w1t + (size_t)H0 * KPAD;                // 256*1024 bf16
    unsigned short* h   = w2t + (size_t)H1 * H0;                  // 32768*1024 bf16

    hipLaunchKernelGGL(cvt_x, dim3((N_ROWS * 384) / 256), dim3(256), 0, stream, x, xb);
    hipLaunchKernelGGL(transpose_cvt, dim3(H0 / 32, KPAD / 32), dim3(32, 8), 0, stream,
                       W1, D_IN, H0, KPAD, w1t);
    hipLaunchKernelGGL(transpose_cvt, dim3(H1 / 32, H0 / 32), dim3(32, 8), 0, stream,
                       W2, H0, H1, H0, w2t);
    hipLaunchKernelGGL(gemm1, dim3((N_ROWS / 128) * (H0 / 256)), dim3(256), 0, stream,
                       xb, w1t, b1, h);
    hipLaunchKernelGGL(gemm2, dim3((N_ROWS / 128) * (H1 / 128)), dim3(256), 0, stream,
                       h, w2t, b2, out);
    hipLaunchKernelGGL(cluster_kernel, dim3(N_ROWS / 4), dim3(256), 0, stream,
                       out, clusters, out + (size_t)N_ROWS * H1);
}